// Round 8
// baseline (135.522 us; speedup 1.0000x reference)
//
#include <hip/hip_runtime.h>
#include <hip/hip_bf16.h>

// Problem constants
static constexpr int kB   = 8;
static constexpr int kP   = 196;
static constexpr int kL   = 80;
static constexpr int kD1  = 2048;
static constexpr int kD2  = 300;
static constexpr int kD2p = 320;       // K of p2 padded to multiple of 64
static constexpr int kATT = 1024;
static constexpr int kM   = kB * kP;   // 1568 rows of p1
static constexpr int kR2  = kB * kL;   // 640 rows of p2
static constexpr int kOut = kB * kL * kP;        // 125440 outputs
static constexpr int kASplit = 16;     // alpha: a-dim split across blocks
static constexpr int kAChunk = kATT / kASplit;   // 64
static constexpr int kLPer   = 5;      // l-values per thread (16 groups x 5 = 80)
static constexpr int kVPart  = 16;     // c-slices for v partials
static constexpr int kPadA   = kAChunk + 4;      // 68: LDS row pad (bank shift)

static constexpr float kTanhScale = 2.8853900817779268f;  // 2*log2(e)

// fp32 -> bf16 round-to-nearest-even
__device__ __forceinline__ unsigned short f2bf(float x) {
    union { float f; unsigned int u; } c; c.f = x;
    unsigned int r = c.u + 0x7fffu + ((c.u >> 16) & 1u);
    return (unsigned short)(r >> 16);
}

typedef __attribute__((ext_vector_type(8))) short  bf16x8;
typedef __attribute__((ext_vector_type(4))) float  f32x4;

__device__ __forceinline__ void load_lds16(const void* g, void* l) {
    __builtin_amdgcn_global_load_lds(
        (const __attribute__((address_space(1))) void*)g,
        (__attribute__((address_space(3))) void*)l, 16, 0, 0);
}

__device__ __forceinline__ float sigl(float uw) {   // rcp(exp2(uw)+1)
    return __builtin_amdgcn_rcpf(__builtin_amdgcn_exp2f(uw) + 1.0f);
}

// ---------------------------------------------------------------------------
// Fused prep: blocks [0, kCastBlocks) cast x1,W1 (float4-wide) and cast+pad
// x2,W2 (K 300->320); blocks [kCastBlocks, +64) compute v PARTIALS
// (atomic-free: block (ax,cg) owns a-chunk ax*256.. and c-slice cg*64..,
// writes vpart[cg][a]) and beta = dot(wt,bh)+bt.
// ---------------------------------------------------------------------------
static constexpr int kN4a = kM * kD1 / 4;      // x1 float4s
static constexpr int kN4b = kATT * kD1 / 4;    // W1 float4s
static constexpr int kN1  = kR2 * kD2p;        // x2b elems (padded)
static constexpr int kN2  = kATT * kD2p;       // W2b elems (padded)
static constexpr int kCastBlocks =
    (kN4a + kN4b + kN1 + kN2 + 255) / 256;

__global__ __launch_bounds__(256) void prep_kernel(
        const float* __restrict__ x1, unsigned short* __restrict__ x1b,
        const float* __restrict__ W1, unsigned short* __restrict__ W1b,
        const float* __restrict__ x2, unsigned short* __restrict__ x2b,
        const float* __restrict__ W2, unsigned short* __restrict__ W2b,
        const float* __restrict__ Wh, const float* __restrict__ wt,
        const float* __restrict__ bh, const float* __restrict__ bt,
        float* __restrict__ vpart, float* __restrict__ beta) {
    if (blockIdx.x >= kCastBlocks) {           // ---- v/beta part (64 blocks)
        int bid = blockIdx.x - kCastBlocks;    // 0..63
        int ax  = bid & 3;                     // a-chunk of 256
        int cg  = bid >> 2;                    // c-slice index 0..15
        int c0  = cg * 64;
        int a   = ax * 256 + threadIdx.x;
        float acc = 0.0f;
        #pragma unroll 8
        for (int c = c0; c < c0 + 64; ++c)
            acc = fmaf(wt[c], Wh[(size_t)c * kATT + a], acc);
        vpart[(size_t)cg * kATT + a] = acc;    // plain store, no atomics
        if (bid == 0 && threadIdx.x < 64) {
            float pb = 0.0f;
            #pragma unroll 4
            for (int c = threadIdx.x; c < kATT; c += 64)
                pb = fmaf(wt[c], bh[c], pb);
            #pragma unroll
            for (int off = 32; off > 0; off >>= 1)
                pb += __shfl_down(pb, off, 64);
            if (threadIdx.x == 0) beta[0] = pb + bt[0];
        }
        return;
    }
    int i = blockIdx.x * 256 + threadIdx.x;    // ---- cast part
    if (i < kN4a) {
        float4 f = ((const float4*)x1)[i];
        ushort4 o = { f2bf(f.x), f2bf(f.y), f2bf(f.z), f2bf(f.w) };
        ((ushort4*)x1b)[i] = o;
    } else if ((i -= kN4a) < kN4b) {
        float4 f = ((const float4*)W1)[i];
        ushort4 o = { f2bf(f.x), f2bf(f.y), f2bf(f.z), f2bf(f.w) };
        ((ushort4*)W1b)[i] = o;
    } else if ((i -= kN4b) < kN1) {
        int r = i / kD2p, c = i - r * kD2p;
        x2b[i] = (c < kD2) ? f2bf(x2[(size_t)r * kD2 + c]) : (unsigned short)0;
    } else if ((i -= kN1) < kN2) {
        int r = i / kD2p, c = i - r * kD2p;
        W2b[i] = (c < kD2) ? f2bf(W2[(size_t)r * kD2 + c]) : (unsigned short)0;
    }
}

// ---------------------------------------------------------------------------
// Fused GEMM dispatch:
//   [0, kP1Blocks): p1 128x128 dbuf, K-split 2 -> p1a/p1b, XCD-CHUNKED:
//       kP1Blocks = 208 = 8 XCDs x 26, and 26 blocks = exactly one nx-panel
//       (13 mx x 2 ks).  Round-robin dispatch puts bid%8 on XCD (bid%8), so
//       remap t2 = (bid&7)*26 + (bid>>3): XCD x owns nx == x entirely ->
//       its W1b panel (0.5 MB) is fetched once into that XCD's L2 instead
//       of 8x across all L2s (T1 mechanism).  Pure bijective permutation.
//   [+kP2Blocks):   p2 64x64 (small, unswizzled)
//   [+kInitBlocks): out[i] = beta
//   [+kVBlocks):    v[a] = sum_g vpart[g][a]
// ---------------------------------------------------------------------------
static constexpr int kP1Mt      = (kM + 127) / 128;              // 13
static constexpr int kP1Blocks  = kP1Mt * (kATT / 128) * 2;      // 208 (K-split 2)
static constexpr int kP2Blocks  = (kR2 / 64) * (kATT / 64);      // 160
static constexpr int kInitBlocks = (kOut + 255) / 256;           // 490
static constexpr int kVBlocks   = kATT / 256;                    // 4
static constexpr int kKHalf     = kD1 / 2;                       // 1024

__global__ __launch_bounds__(256) void gemm_all_kernel(
        const unsigned short* __restrict__ x2b, const unsigned short* __restrict__ W2b,
        float* __restrict__ p2w,
        const unsigned short* __restrict__ x1b, const unsigned short* __restrict__ W1b,
        float* __restrict__ p1a, float* __restrict__ p1b,
        const float* __restrict__ beta, float* __restrict__ outp,
        const float* __restrict__ vpart, float* __restrict__ v) {
    __shared__ unsigned short As2[2][128 * 64];   // 2 x 16 KB
    __shared__ unsigned short Bs2[2][128 * 64];   // 2 x 16 KB

    const int bid  = blockIdx.x;
    const int tid  = threadIdx.x;
    const int lane = tid & 63;
    const int wv   = tid >> 6;

    if (bid >= kP1Blocks + kP2Blocks) {
        int r = bid - kP1Blocks - kP2Blocks;
        if (r < kInitBlocks) {                 // ---- out = beta init
            int i = r * 256 + tid;
            if (i < kOut) outp[i] = beta[0];
        } else {                               // ---- v = sum of vpart slices
            int a = (r - kInitBlocks) * 256 + tid;
            float s = 0.0f;
            #pragma unroll
            for (int g = 0; g < kVPart; ++g)
                s += vpart[(size_t)g * kATT + a];
            v[a] = s;
        }
        return;
    }

    if (bid < kP1Blocks) {                     // ---- p1: 128x128 dbuf path
        // XCD-chunked remap: XCD (bid&7) owns one full nx panel.
        const int t2 = (bid & 7) * 26 + (bid >> 3);   // 0..207 bijective
        const int ks = t2 & 1;                 // K-split half
        const int t  = t2 >> 1;                // 0..103
        const int mx = t % kP1Mt, nx = t / kP1Mt;
        const int m0 = mx * 128, n0 = nx * 128;
        const int kBeg = ks * kKHalf;

        const int srow = tid >> 3;                         // 0..31
        const int kx   = ((tid & 7) ^ (srow & 7)) * 8;     // swizzled k-elems
        int ar[4], br[4];
        #pragma unroll
        for (int q = 0; q < 4; ++q) {
            ar[q] = min(m0 + srow + q * 32, kM - 1);
            br[q] = n0 + srow + q * 32;
        }
        const int wr = (wv >> 1) * 64;         // wave row offset in tile
        const int wc = (wv & 1) * 64;          // wave col offset in tile

        f32x4 acc[4][4] = {};

        // prologue: stage buf 0
        #pragma unroll
        for (int q = 0; q < 4; ++q) {
            load_lds16(x1b + (size_t)ar[q] * kD1 + kBeg + kx,
                       (char*)As2[0] + (tid + q * 256) * 16);
            load_lds16(W1b + (size_t)br[q] * kD1 + kBeg + kx,
                       (char*)Bs2[0] + (tid + q * 256) * 16);
        }
        __syncthreads();

        int buf = 0;
        for (int k0 = 0; k0 < kKHalf; k0 += 64) {
            if (k0 + 64 < kKHalf) {            // issue next-tile loads FIRST
                const int kp = kBeg + k0 + 64;
                #pragma unroll
                for (int q = 0; q < 4; ++q) {
                    load_lds16(x1b + (size_t)ar[q] * kD1 + kp + kx,
                               (char*)As2[buf ^ 1] + (tid + q * 256) * 16);
                    load_lds16(W1b + (size_t)br[q] * kD1 + kp + kx,
                               (char*)Bs2[buf ^ 1] + (tid + q * 256) * 16);
                }
            }
            const char* Ap = (const char*)As2[buf];
            const char* Bp = (const char*)Bs2[buf];
            #pragma unroll
            for (int kk = 0; kk < 2; ++kk) {
                bf16x8 af[4], bf[4];
                #pragma unroll
                for (int i = 0; i < 4; ++i) {
                    int r   = wr + i * 16 + (lane & 15);
                    int col = (kk * 64 + (lane >> 4) * 16) ^ ((r & 7) << 4);
                    af[i] = *(const bf16x8*)(Ap + r * 128 + col);
                }
                #pragma unroll
                for (int j = 0; j < 4; ++j) {
                    int r   = wc + j * 16 + (lane & 15);
                    int col = (kk * 64 + (lane >> 4) * 16) ^ ((r & 7) << 4);
                    bf[j] = *(const bf16x8*)(Bp + r * 128 + col);
                }
                #pragma unroll
                for (int i = 0; i < 4; ++i)
                    #pragma unroll
                    for (int j = 0; j < 4; ++j)
                        acc[i][j] = __builtin_amdgcn_mfma_f32_16x16x32_bf16(
                                        af[i], bf[j], acc[i][j], 0, 0, 0);
            }
            __syncthreads();                   // drains staged loads too
            buf ^= 1;
        }

        float* Co = ks ? p1b : p1a;
        #pragma unroll
        for (int i = 0; i < 4; ++i)
            #pragma unroll
            for (int j = 0; j < 4; ++j)
                #pragma unroll
                for (int r = 0; r < 4; ++r) {
                    int m = m0 + wr + i * 16 + (lane >> 4) * 4 + r;
                    int n = n0 + wc + j * 16 + (lane & 15);
                    if (m < kM) Co[(size_t)m * kATT + n] = kTanhScale * acc[i][j][r];
                }
        return;
    }

    // ---- p2: legacy 64x64 path (small: 0.42 GF)
    {
        const int l  = bid - kP1Blocks;
        const int mx = l % (kR2 / 64), nx = l / (kR2 / 64);
        const int m0 = mx * 64, n0 = nx * 64;
        unsigned short* As = As2[0];
        unsigned short* Bs = Bs2[0];

        const int mh = (wv >> 1) * 32;
        const int nh = (wv & 1) * 32;
        const int row0 = tid >> 3;
        const int kx   = ((tid & 7) ^ (row0 & 7)) * 8;
        const int ar0 = min(m0 + row0, kR2 - 1), ar1 = min(m0 + row0 + 32, kR2 - 1);
        const int br0 = n0 + row0,               br1 = n0 + row0 + 32;

        f32x4 acc[2][2] = {};
        for (int k0 = 0; k0 < kD2p; k0 += 64) {
            load_lds16(x2b + (size_t)ar0 * kD2p + k0 + kx, (char*)As + tid * 16);
            load_lds16(x2b + (size_t)ar1 * kD2p + k0 + kx, (char*)As + (tid + 256) * 16);
            load_lds16(W2b + (size_t)br0 * kD2p + k0 + kx, (char*)Bs + tid * 16);
            load_lds16(W2b + (size_t)br1 * kD2p + k0 + kx, (char*)Bs + (tid + 256) * 16);
            __syncthreads();

            #pragma unroll
            for (int kk = 0; kk < 2; ++kk) {
                bf16x8 af[2], bf[2];
                #pragma unroll
                for (int i = 0; i < 2; ++i) {
                    int r   = mh + i * 16 + (lane & 15);
                    int col = (kk * 64 + (lane >> 4) * 16) ^ ((r & 7) << 4);
                    af[i] = *(const bf16x8*)((const char*)As + r * 128 + col);
                }
                #pragma unroll
                for (int j = 0; j < 2; ++j) {
                    int r   = nh + j * 16 + (lane & 15);
                    int col = (kk * 64 + (lane >> 4) * 16) ^ ((r & 7) << 4);
                    bf[j] = *(const bf16x8*)((const char*)Bs + r * 128 + col);
                }
                #pragma unroll
                for (int i = 0; i < 2; ++i)
                    #pragma unroll
                    for (int j = 0; j < 2; ++j)
                        acc[i][j] = __builtin_amdgcn_mfma_f32_16x16x32_bf16(
                                        af[i], bf[j], acc[i][j], 0, 0, 0);
            }
            __syncthreads();
        }

        #pragma unroll
        for (int i = 0; i < 2; ++i)
            #pragma unroll
            for (int j = 0; j < 2; ++j)
                #pragma unroll
                for (int r = 0; r < 4; ++r) {
                    int m = m0 + mh + i * 16 + (lane >> 4) * 4 + r;
                    int n = n0 + nh + j * 16 + (lane & 15);
                    if (m < kR2) p2w[(size_t)m * kATT + n] = acc[i][j][r];
                }
    }
}

// ---------------------------------------------------------------------------
// alpha v5 (unchanged from round 7 -- empirical best):
//   R4 structure (ptile 16, a-split 16), v on the scalar/uniform path,
//   us rows padded to 68 floats (2-way alias = free), w reads broadcast.
//   sum_a v*tanh = sumV - 2*sum_a v*rcp(exp2(u*w)+1),  u pre-scaled 2log2e.
// grid (13, kB, 16); block 256 = 16 tp x 16 lg (5 l each).
// Each block atomicAdds into out (pre-set to beta by gemm dispatch).
// ---------------------------------------------------------------------------
__global__ __launch_bounds__(256) void alpha_kernel(
        const float* __restrict__ p1A, const float* __restrict__ p1B,
        const float* __restrict__ p2,
        const float* __restrict__ v, float* __restrict__ outp) {
    __shared__ float us[16][kPadA];          // 16 x 68 x 4 = 4.25 KB
    __shared__ float wsm[kL][kPadA];         // 80 x 68 x 4 = 21.25 KB
    const int b     = blockIdx.y;
    const int as    = blockIdx.z;            // 0..15
    const int aBase = as * kAChunk;
    const int p0    = blockIdx.x * 16;
    const int tid   = threadIdx.x;
    const int tp    = tid & 15;              // p lane
    const int lg    = tid >> 4;              // l-group: l = lg*5 + j

    // ---- stage u (16 rows x 16 float4 cols, one per thread), summing halves
    {
        int row = tid >> 4, col = tid & 15;
        int gp  = min(p0 + row, kP - 1);
        size_t base = ((size_t)(b * kP + gp)) * kATT + aBase + col * 4;
        float4 ua = *(const float4*)(p1A + base);
        float4 ub = *(const float4*)(p1B + base);
        float4 s  = { ua.x + ub.x, ua.y + ub.y, ua.z + ub.z, ua.w + ub.w };
        *(float4*)&us[row][col * 4] = s;
    }
    // ---- stage w (80 rows x 16 float4 cols = 1280 float4, 5 per thread)
    #pragma unroll
    for (int q = 0; q < 5; ++q) {
        int idx = q * 256 + tid;             // 0..1279
        int row = idx >> 4, col = idx & 15;
        size_t base = ((size_t)(b * kL + row)) * kATT + aBase + col * 4;
        *(float4*)&wsm[row][col * 4] = *(const float4*)(p2 + base);
    }
    __syncthreads();

    float sumV = 0.0f;
    float acc[kLPer] = {};
    #pragma unroll 4
    for (int a4 = 0; a4 < kAChunk / 4; ++a4) {
        const float4 vv = *(const float4*)(v + aBase + a4 * 4);  // uniform
        sumV += vv.x + vv.y + vv.z + vv.w;
        float4 u = *(const float4*)&us[tp][a4 * 4];
        #pragma unroll
        for (int j = 0; j < kLPer; ++j) {
            float4 w = *(const float4*)&wsm[lg * kLPer + j][a4 * 4];
            acc[j] = fmaf(vv.x, sigl(u.x * w.x), acc[j]);
            acc[j] = fmaf(vv.y, sigl(u.y * w.y), acc[j]);
            acc[j] = fmaf(vv.z, sigl(u.z * w.z), acc[j]);
            acc[j] = fmaf(vv.w, sigl(u.w * w.w), acc[j]);
        }
    }

    const int p = p0 + tp;
    if (p < kP) {
        float* po = outp + ((size_t)b * kL + lg * kLPer) * kP + p;
        #pragma unroll
        for (int j = 0; j < kLPer; ++j)
            atomicAdd(&po[(size_t)j * kP], sumV - 2.0f * acc[j]);
    }
}

// ---------------------------------------------------------------------------
extern "C" void kernel_launch(void* const* d_in, const int* in_sizes, int n_in,
                              void* d_out, int out_size, void* d_ws, size_t ws_size,
                              hipStream_t stream) {
    const float* x1 = (const float*)d_in[0];
    const float* x2 = (const float*)d_in[1];
    const float* W1 = (const float*)d_in[2];
    const float* W2 = (const float*)d_in[3];
    const float* Wh = (const float*)d_in[4];
    const float* bh = (const float*)d_in[5];
    const float* wt = (const float*)d_in[6];
    const float* bt = (const float*)d_in[7];
    float* out = (float*)d_out;

    // workspace layout (floats first, then bf16):
    // v[1024] | vpart[16*1024] | beta pad->64 | p2w[640*1024]
    // | p1a[1568*1024] | p1b[1568*1024] | x1b | W1b | x2b | W2b   (~27 MB)
    float* ws    = (float*)d_ws;
    float* v     = ws;
    float* vpart = ws + 1024;
    float* beta  = vpart + (size_t)kVPart * kATT;
    float* p2w   = beta + 64;
    float* p1a   = p2w + (size_t)kR2 * kATT;
    float* p1b   = p1a + (size_t)kM * kATT;
    unsigned short* x1b = (unsigned short*)(p1b + (size_t)kM * kATT);
    unsigned short* W1b = x1b + (size_t)kM * kD1;
    unsigned short* x2b = W1b + (size_t)kATT * kD1;
    unsigned short* W2b = x2b + (size_t)kR2 * kD2p;

    prep_kernel<<<dim3(kCastBlocks + 64), 256, 0, stream>>>(
        x1, x1b, W1, W1b, x2, x2b, W2, W2b, Wh, wt, bh, bt, vpart, beta);
    gemm_all_kernel<<<dim3(kP1Blocks + kP2Blocks + kInitBlocks + kVBlocks),
                     256, 0, stream>>>(
        x2b, W2b, p2w, x1b, W1b, p1a, p1b, beta, out, vpart, v);
    alpha_kernel<<<dim3((kP + 15) / 16, kB, kASplit), 256, 0, stream>>>(
        p1a, p1b, p2w, v, out);
}

// Round 10
// 134.323 us; speedup vs baseline: 1.0089x; 1.0089x over previous
//
#include <hip/hip_runtime.h>
#include <hip/hip_bf16.h>

// Problem constants
static constexpr int kB   = 8;
static constexpr int kP   = 196;
static constexpr int kL   = 80;
static constexpr int kD1  = 2048;
static constexpr int kD2  = 300;
static constexpr int kD2p = 320;       // K of p2 padded to multiple of 64
static constexpr int kATT = 1024;
static constexpr int kM   = kB * kP;   // 1568 rows of p1
static constexpr int kR2  = kB * kL;   // 640 rows of p2
static constexpr int kOut = kB * kL * kP;        // 125440 outputs
static constexpr int kASplit = 16;     // alpha: a-dim split across blocks
static constexpr int kAChunk = kATT / kASplit;   // 64
static constexpr int kLPer   = 5;      // l-values per thread (16 groups x 5 = 80)
static constexpr int kVPart  = 16;     // c-slices for v partials
static constexpr int kPadA   = kAChunk + 4;      // 68: LDS row pad (us only)

static constexpr float kTanhScale = 2.8853900817779268f;  // 2*log2(e)

// fp32 -> bf16 round-to-nearest-even
__device__ __forceinline__ unsigned short f2bf(float x) {
    union { float f; unsigned int u; } c; c.f = x;
    unsigned int r = c.u + 0x7fffu + ((c.u >> 16) & 1u);
    return (unsigned short)(r >> 16);
}

typedef __attribute__((ext_vector_type(8))) short  bf16x8;
typedef __attribute__((ext_vector_type(4))) float  f32x4;

__device__ __forceinline__ void load_lds16(const void* g, void* l) {
    __builtin_amdgcn_global_load_lds(
        (const __attribute__((address_space(1))) void*)g,
        (__attribute__((address_space(3))) void*)l, 16, 0, 0);
}

__device__ __forceinline__ float sigl(float uw) {   // rcp(exp2(uw)+1)
    return __builtin_amdgcn_rcpf(__builtin_amdgcn_exp2f(uw) + 1.0f);
}

// ---------------------------------------------------------------------------
// Fused prep: blocks [0, kCastBlocks) cast x1,W1 (float4-wide) and cast+pad
// x2,W2 (K 300->320); blocks [kCastBlocks, +64) compute v PARTIALS
// (atomic-free: block (ax,cg) owns a-chunk ax*256.. and c-slice cg*64..,
// writes vpart[cg][a]) and beta = dot(wt,bh)+bt.
// ---------------------------------------------------------------------------
static constexpr int kN4a = kM * kD1 / 4;      // x1 float4s
static constexpr int kN4b = kATT * kD1 / 4;    // W1 float4s
static constexpr int kN1  = kR2 * kD2p;        // x2b elems (padded)
static constexpr int kN2  = kATT * kD2p;       // W2b elems (padded)
static constexpr int kCastBlocks =
    (kN4a + kN4b + kN1 + kN2 + 255) / 256;

__global__ __launch_bounds__(256) void prep_kernel(
        const float* __restrict__ x1, unsigned short* __restrict__ x1b,
        const float* __restrict__ W1, unsigned short* __restrict__ W1b,
        const float* __restrict__ x2, unsigned short* __restrict__ x2b,
        const float* __restrict__ W2, unsigned short* __restrict__ W2b,
        const float* __restrict__ Wh, const float* __restrict__ wt,
        const float* __restrict__ bh, const float* __restrict__ bt,
        float* __restrict__ vpart, float* __restrict__ beta) {
    if (blockIdx.x >= kCastBlocks) {           // ---- v/beta part (64 blocks)
        int bid = blockIdx.x - kCastBlocks;    // 0..63
        int ax  = bid & 3;                     // a-chunk of 256
        int cg  = bid >> 2;                    // c-slice index 0..15
        int c0  = cg * 64;
        int a   = ax * 256 + threadIdx.x;
        float acc = 0.0f;
        #pragma unroll 8
        for (int c = c0; c < c0 + 64; ++c)
            acc = fmaf(wt[c], Wh[(size_t)c * kATT + a], acc);
        vpart[(size_t)cg * kATT + a] = acc;    // plain store, no atomics
        if (bid == 0 && threadIdx.x < 64) {
            float pb = 0.0f;
            #pragma unroll 4
            for (int c = threadIdx.x; c < kATT; c += 64)
                pb = fmaf(wt[c], bh[c], pb);
            #pragma unroll
            for (int off = 32; off > 0; off >>= 1)
                pb += __shfl_down(pb, off, 64);
            if (threadIdx.x == 0) beta[0] = pb + bt[0];
        }
        return;
    }
    int i = blockIdx.x * 256 + threadIdx.x;    // ---- cast part
    if (i < kN4a) {
        float4 f = ((const float4*)x1)[i];
        ushort4 o = { f2bf(f.x), f2bf(f.y), f2bf(f.z), f2bf(f.w) };
        ((ushort4*)x1b)[i] = o;
    } else if ((i -= kN4a) < kN4b) {
        float4 f = ((const float4*)W1)[i];
        ushort4 o = { f2bf(f.x), f2bf(f.y), f2bf(f.z), f2bf(f.w) };
        ((ushort4*)W1b)[i] = o;
    } else if ((i -= kN4b) < kN1) {
        int r = i / kD2p, c = i - r * kD2p;
        x2b[i] = (c < kD2) ? f2bf(x2[(size_t)r * kD2 + c]) : (unsigned short)0;
    } else if ((i -= kN1) < kN2) {
        int r = i / kD2p, c = i - r * kD2p;
        W2b[i] = (c < kD2) ? f2bf(W2[(size_t)r * kD2 + c]) : (unsigned short)0;
    }
}

// ---------------------------------------------------------------------------
// Fused GEMM dispatch (R7 mapping -- XCD chunking was null, R8):
//   [0, kP1Blocks): p1 128x128 dbuf, K-split 2 -> p1a/p1b
//   [+kP2Blocks):   p2 64x64
//   [+kInitBlocks): out[i] = beta
//   [+kVBlocks):    v[a] = sum_g vpart[g][a]
// ---------------------------------------------------------------------------
static constexpr int kP1Mt      = (kM + 127) / 128;              // 13
static constexpr int kP1Blocks  = kP1Mt * (kATT / 128) * 2;      // 208 (K-split 2)
static constexpr int kP2Blocks  = (kR2 / 64) * (kATT / 64);      // 160
static constexpr int kInitBlocks = (kOut + 255) / 256;           // 490
static constexpr int kVBlocks   = kATT / 256;                    // 4
static constexpr int kKHalf     = kD1 / 2;                       // 1024

__global__ __launch_bounds__(256) void gemm_all_kernel(
        const unsigned short* __restrict__ x2b, const unsigned short* __restrict__ W2b,
        float* __restrict__ p2w,
        const unsigned short* __restrict__ x1b, const unsigned short* __restrict__ W1b,
        float* __restrict__ p1a, float* __restrict__ p1b,
        const float* __restrict__ beta, float* __restrict__ outp,
        const float* __restrict__ vpart, float* __restrict__ v) {
    __shared__ unsigned short As2[2][128 * 64];   // 2 x 16 KB
    __shared__ unsigned short Bs2[2][128 * 64];   // 2 x 16 KB

    const int bid  = blockIdx.x;
    const int tid  = threadIdx.x;
    const int lane = tid & 63;
    const int wv   = tid >> 6;

    if (bid >= kP1Blocks + kP2Blocks) {
        int r = bid - kP1Blocks - kP2Blocks;
        if (r < kInitBlocks) {                 // ---- out = beta init
            int i = r * 256 + tid;
            if (i < kOut) outp[i] = beta[0];
        } else {                               // ---- v = sum of vpart slices
            int a = (r - kInitBlocks) * 256 + tid;
            float s = 0.0f;
            #pragma unroll
            for (int g = 0; g < kVPart; ++g)
                s += vpart[(size_t)g * kATT + a];
            v[a] = s;
        }
        return;
    }

    if (bid < kP1Blocks) {                     // ---- p1: 128x128 dbuf path
        const int l  = bid;
        const int ks = l & 1;                  // K-split half
        const int t  = l >> 1;                 // 0..103
        const int mx = t % kP1Mt, nx = t / kP1Mt;
        const int m0 = mx * 128, n0 = nx * 128;
        const int kBeg = ks * kKHalf;

        const int srow = tid >> 3;                         // 0..31
        const int kx   = ((tid & 7) ^ (srow & 7)) * 8;     // swizzled k-elems
        int ar[4], br[4];
        #pragma unroll
        for (int q = 0; q < 4; ++q) {
            ar[q] = min(m0 + srow + q * 32, kM - 1);
            br[q] = n0 + srow + q * 32;
        }
        const int wr = (wv >> 1) * 64;         // wave row offset in tile
        const int wc = (wv & 1) * 64;          // wave col offset in tile

        f32x4 acc[4][4] = {};

        // prologue: stage buf 0
        #pragma unroll
        for (int q = 0; q < 4; ++q) {
            load_lds16(x1b + (size_t)ar[q] * kD1 + kBeg + kx,
                       (char*)As2[0] + (tid + q * 256) * 16);
            load_lds16(W1b + (size_t)br[q] * kD1 + kBeg + kx,
                       (char*)Bs2[0] + (tid + q * 256) * 16);
        }
        __syncthreads();

        int buf = 0;
        for (int k0 = 0; k0 < kKHalf; k0 += 64) {
            if (k0 + 64 < kKHalf) {            // issue next-tile loads FIRST
                const int kp = kBeg + k0 + 64;
                #pragma unroll
                for (int q = 0; q < 4; ++q) {
                    load_lds16(x1b + (size_t)ar[q] * kD1 + kp + kx,
                               (char*)As2[buf ^ 1] + (tid + q * 256) * 16);
                    load_lds16(W1b + (size_t)br[q] * kD1 + kp + kx,
                               (char*)Bs2[buf ^ 1] + (tid + q * 256) * 16);
                }
            }
            const char* Ap = (const char*)As2[buf];
            const char* Bp = (const char*)Bs2[buf];
            #pragma unroll
            for (int kk = 0; kk < 2; ++kk) {
                bf16x8 af[4], bf[4];
                #pragma unroll
                for (int i = 0; i < 4; ++i) {
                    int r   = wr + i * 16 + (lane & 15);
                    int col = (kk * 64 + (lane >> 4) * 16) ^ ((r & 7) << 4);
                    af[i] = *(const bf16x8*)(Ap + r * 128 + col);
                }
                #pragma unroll
                for (int j = 0; j < 4; ++j) {
                    int r   = wc + j * 16 + (lane & 15);
                    int col = (kk * 64 + (lane >> 4) * 16) ^ ((r & 7) << 4);
                    bf[j] = *(const bf16x8*)(Bp + r * 128 + col);
                }
                #pragma unroll
                for (int i = 0; i < 4; ++i)
                    #pragma unroll
                    for (int j = 0; j < 4; ++j)
                        acc[i][j] = __builtin_amdgcn_mfma_f32_16x16x32_bf16(
                                        af[i], bf[j], acc[i][j], 0, 0, 0);
            }
            __syncthreads();                   // drains staged loads too
            buf ^= 1;
        }

        float* Co = ks ? p1b : p1a;
        #pragma unroll
        for (int i = 0; i < 4; ++i)
            #pragma unroll
            for (int j = 0; j < 4; ++j)
                #pragma unroll
                for (int r = 0; r < 4; ++r) {
                    int m = m0 + wr + i * 16 + (lane >> 4) * 4 + r;
                    int n = n0 + wc + j * 16 + (lane & 15);
                    if (m < kM) Co[(size_t)m * kATT + n] = kTanhScale * acc[i][j][r];
                }
        return;
    }

    // ---- p2: legacy 64x64 path (small: 0.42 GF)
    {
        const int l  = bid - kP1Blocks;
        const int mx = l % (kR2 / 64), nx = l / (kR2 / 64);
        const int m0 = mx * 64, n0 = nx * 64;
        unsigned short* As = As2[0];
        unsigned short* Bs = Bs2[0];

        const int mh = (wv >> 1) * 32;
        const int nh = (wv & 1) * 32;
        const int row0 = tid >> 3;
        const int kx   = ((tid & 7) ^ (row0 & 7)) * 8;
        const int ar0 = min(m0 + row0, kR2 - 1), ar1 = min(m0 + row0 + 32, kR2 - 1);
        const int br0 = n0 + row0,               br1 = n0 + row0 + 32;

        f32x4 acc[2][2] = {};
        for (int k0 = 0; k0 < kD2p; k0 += 64) {
            load_lds16(x2b + (size_t)ar0 * kD2p + k0 + kx, (char*)As + tid * 16);
            load_lds16(x2b + (size_t)ar1 * kD2p + k0 + kx, (char*)As + (tid + 256) * 16);
            load_lds16(W2b + (size_t)br0 * kD2p + k0 + kx, (char*)Bs + tid * 16);
            load_lds16(W2b + (size_t)br1 * kD2p + k0 + kx, (char*)Bs + (tid + 256) * 16);
            __syncthreads();

            #pragma unroll
            for (int kk = 0; kk < 2; ++kk) {
                bf16x8 af[2], bf[2];
                #pragma unroll
                for (int i = 0; i < 2; ++i) {
                    int r   = mh + i * 16 + (lane & 15);
                    int col = (kk * 64 + (lane >> 4) * 16) ^ ((r & 7) << 4);
                    af[i] = *(const bf16x8*)((const char*)As + r * 128 + col);
                }
                #pragma unroll
                for (int j = 0; j < 2; ++j) {
                    int r   = nh + j * 16 + (lane & 15);
                    int col = (kk * 64 + (lane >> 4) * 16) ^ ((r & 7) << 4);
                    bf[j] = *(const bf16x8*)((const char*)Bs + r * 128 + col);
                }
                #pragma unroll
                for (int i = 0; i < 2; ++i)
                    #pragma unroll
                    for (int j = 0; j < 2; ++j)
                        acc[i][j] = __builtin_amdgcn_mfma_f32_16x16x32_bf16(
                                        af[i], bf[j], acc[i][j], 0, 0, 0);
            }
            __syncthreads();
        }

        #pragma unroll
        for (int i = 0; i < 2; ++i)
            #pragma unroll
            for (int j = 0; j < 2; ++j)
                #pragma unroll
                for (int r = 0; r < 4; ++r) {
                    int m = m0 + mh + i * 16 + (lane >> 4) * 4 + r;
                    int n = n0 + nh + j * 16 + (lane & 15);
                    if (m < kR2) p2w[(size_t)m * kATT + n] = acc[i][j][r];
                }
    }
}

// ---------------------------------------------------------------------------
// alpha v6 = R7 alpha + DMA w-staging:
//   - wsm is a raw copy of p2w rows -> staged via global_load_lds (no VGPR
//     round-trip, no ds_write; Common-mistake #1).  Requires lane-linear LDS
//     dest, so wsm is UNPADDED [80][64] -- safe because w reads are 16-lane
//     same-address broadcasts (4 distinct addrs/wave), conflict-free at any
//     row stride.  us keeps the 68-float pad (16 lanes read 16 different
//     rows at one column) and manual staging (needs the uA+uB add).
//   - v on the scalar/uniform path (R7).
//   sum_a v*tanh = sumV - 2*sum_a v*rcp(exp2(u*w)+1),  u pre-scaled 2log2e.
// grid (13, kB, 16); block 256 = 16 tp x 16 lg (5 l each).
// Each block atomicAdds into out (pre-set to beta by gemm dispatch).
// ---------------------------------------------------------------------------
__global__ __launch_bounds__(256) void alpha_kernel(
        const float* __restrict__ p1A, const float* __restrict__ p1B,
        const float* __restrict__ p2,
        const float* __restrict__ v, float* __restrict__ outp) {
    __shared__ float us[16][kPadA];          // 16 x 68 x 4 = 4.25 KB (padded)
    __shared__ float wsm[kL][kAChunk];       // 80 x 64 x 4 = 20 KB (linear)
    const int b     = blockIdx.y;
    const int as    = blockIdx.z;            // 0..15
    const int aBase = as * kAChunk;
    const int p0    = blockIdx.x * 16;
    const int tid   = threadIdx.x;
    const int tp    = tid & 15;              // p lane
    const int lg    = tid >> 4;              // l-group: l = lg*5 + j

    // ---- stage w via direct global->LDS DMA (5 chunks of 16 B per thread);
    //      dest offset idx*16 is exactly the linear [row][col] layout.
    #pragma unroll
    for (int q = 0; q < 5; ++q) {
        int idx = q * 256 + tid;             // 0..1279
        int row = idx >> 4, col = idx & 15;
        load_lds16(p2 + ((size_t)(b * kL + row)) * kATT + aBase + col * 4,
                   (char*)wsm + (size_t)idx * 16);
    }
    // ---- stage u (16 rows x 16 float4 cols, one per thread), summing halves
    {
        int row = tid >> 4, col = tid & 15;
        int gp  = min(p0 + row, kP - 1);
        size_t base = ((size_t)(b * kP + gp)) * kATT + aBase + col * 4;
        float4 ua = *(const float4*)(p1A + base);
        float4 ub = *(const float4*)(p1B + base);
        float4 s  = { ua.x + ub.x, ua.y + ub.y, ua.z + ub.z, ua.w + ub.w };
        *(float4*)&us[row][col * 4] = s;
    }
    __syncthreads();                         // drains DMA (vmcnt) + ds_write

    float sumV = 0.0f;
    float acc[kLPer] = {};
    #pragma unroll 4
    for (int a4 = 0; a4 < kAChunk / 4; ++a4) {
        const float4 vv = *(const float4*)(v + aBase + a4 * 4);  // uniform
        sumV += vv.x + vv.y + vv.z + vv.w;
        float4 u = *(const float4*)&us[tp][a4 * 4];
        #pragma unroll
        for (int j = 0; j < kLPer; ++j) {
            float4 w = *(const float4*)&wsm[lg * kLPer + j][a4 * 4];
            acc[j] = fmaf(vv.x, sigl(u.x * w.x), acc[j]);
            acc[j] = fmaf(vv.y, sigl(u.y * w.y), acc[j]);
            acc[j] = fmaf(vv.z, sigl(u.z * w.z), acc[j]);
            acc[j] = fmaf(vv.w, sigl(u.w * w.w), acc[j]);
        }
    }

    const int p = p0 + tp;
    if (p < kP) {
        float* po = outp + ((size_t)b * kL + lg * kLPer) * kP + p;
        #pragma unroll
        for (int j = 0; j < kLPer; ++j)
            atomicAdd(&po[(size_t)j * kP], sumV - 2.0f * acc[j]);
    }
}

// ---------------------------------------------------------------------------
extern "C" void kernel_launch(void* const* d_in, const int* in_sizes, int n_in,
                              void* d_out, int out_size, void* d_ws, size_t ws_size,
                              hipStream_t stream) {
    const float* x1 = (const float*)d_in[0];
    const float* x2 = (const float*)d_in[1];
    const float* W1 = (const float*)d_in[2];
    const float* W2 = (const float*)d_in[3];
    const float* Wh = (const float*)d_in[4];
    const float* bh = (const float*)d_in[5];
    const float* wt = (const float*)d_in[6];
    const float* bt = (const float*)d_in[7];
    float* out = (float*)d_out;

    // workspace layout (floats first, then bf16):
    // v[1024] | vpart[16*1024] | beta pad->64 | p2w[640*1024]
    // | p1a[1568*1024] | p1b[1568*1024] | x1b | W1b | x2b | W2b   (~27 MB)
    float* ws    = (float*)d_ws;
    float* v     = ws;
    float* vpart = ws + 1024;
    float* beta  = vpart + (size_t)kVPart * kATT;
    float* p2w   = beta + 64;
    float* p1a   = p2w + (size_t)kR2 * kATT;
    float* p1b   = p1a + (size_t)kM * kATT;
    unsigned short* x1b = (unsigned short*)(p1b + (size_t)kM * kATT);
    unsigned short* W1b = x1b + (size_t)kM * kD1;
    unsigned short* x2b = W1b + (size_t)kATT * kD1;
    unsigned short* W2b = x2b + (size_t)kR2 * kD2p;

    prep_kernel<<<dim3(kCastBlocks + 64), 256, 0, stream>>>(
        x1, x1b, W1, W1b, x2, x2b, W2, W2b, Wh, wt, bh, bt, vpart, beta);
    gemm_all_kernel<<<dim3(kP1Blocks + kP2Blocks + kInitBlocks + kVBlocks),
                     256, 0, stream>>>(
        x2b, W2b, p2w, x1b, W1b, p1a, p1b, beta, out, vpart, v);
    alpha_kernel<<<dim3((kP + 15) / 16, kB, kASplit), 256, 0, stream>>>(
        p1a, p1b, p2w, v, out);
}

// Round 11
// 133.789 us; speedup vs baseline: 1.0129x; 1.0040x over previous
//
#include <hip/hip_runtime.h>
#include <hip/hip_bf16.h>

// Problem constants
static constexpr int kB   = 8;
static constexpr int kP   = 196;
static constexpr int kL   = 80;
static constexpr int kD1  = 2048;
static constexpr int kD2  = 300;
static constexpr int kD2p = 320;       // K of p2 padded to multiple of 64
static constexpr int kATT = 1024;
static constexpr int kM   = kB * kP;   // 1568 rows of p1
static constexpr int kR2  = kB * kL;   // 640 rows of p2
static constexpr int kOut = kB * kL * kP;        // 125440 outputs
static constexpr int kASplit = 16;     // alpha: a-dim split across blocks
static constexpr int kAChunk = kATT / kASplit;   // 64
static constexpr int kLPer   = 5;      // l-values per thread (16 groups x 5 = 80)
static constexpr int kVPart  = 16;     // c-slices for v partials
static constexpr int kPadA   = kAChunk + 4;      // 68: LDS row pad (us only)

static constexpr float kTanhScale = 2.8853900817779268f;  // 2*log2(e)

// fp32 -> bf16 round-to-nearest-even
__device__ __forceinline__ unsigned short f2bf(float x) {
    union { float f; unsigned int u; } c; c.f = x;
    unsigned int r = c.u + 0x7fffu + ((c.u >> 16) & 1u);
    return (unsigned short)(r >> 16);
}

typedef __attribute__((ext_vector_type(8))) short  bf16x8;
typedef __attribute__((ext_vector_type(4))) float  f32x4;
typedef __attribute__((ext_vector_type(2))) float  f32x2;

__device__ __forceinline__ void load_lds16(const void* g, void* l) {
    __builtin_amdgcn_global_load_lds(
        (const __attribute__((address_space(1))) void*)g,
        (__attribute__((address_space(3))) void*)l, 16, 0, 0);
}

// ---------------------------------------------------------------------------
// Fused prep: blocks [0, kCastBlocks) cast x1,W1 (float4-wide) and cast+pad
// x2,W2 (K 300->320); blocks [kCastBlocks, +64) compute v PARTIALS
// (atomic-free: block (ax,cg) owns a-chunk ax*256.. and c-slice cg*64..,
// writes vpart[cg][a]) and beta = dot(wt,bh)+bt.
// ---------------------------------------------------------------------------
static constexpr int kN4a = kM * kD1 / 4;      // x1 float4s
static constexpr int kN4b = kATT * kD1 / 4;    // W1 float4s
static constexpr int kN1  = kR2 * kD2p;        // x2b elems (padded)
static constexpr int kN2  = kATT * kD2p;       // W2b elems (padded)
static constexpr int kCastBlocks =
    (kN4a + kN4b + kN1 + kN2 + 255) / 256;

__global__ __launch_bounds__(256) void prep_kernel(
        const float* __restrict__ x1, unsigned short* __restrict__ x1b,
        const float* __restrict__ W1, unsigned short* __restrict__ W1b,
        const float* __restrict__ x2, unsigned short* __restrict__ x2b,
        const float* __restrict__ W2, unsigned short* __restrict__ W2b,
        const float* __restrict__ Wh, const float* __restrict__ wt,
        const float* __restrict__ bh, const float* __restrict__ bt,
        float* __restrict__ vpart, float* __restrict__ beta) {
    if (blockIdx.x >= kCastBlocks) {           // ---- v/beta part (64 blocks)
        int bid = blockIdx.x - kCastBlocks;    // 0..63
        int ax  = bid & 3;                     // a-chunk of 256
        int cg  = bid >> 2;                    // c-slice index 0..15
        int c0  = cg * 64;
        int a   = ax * 256 + threadIdx.x;
        float acc = 0.0f;
        #pragma unroll 8
        for (int c = c0; c < c0 + 64; ++c)
            acc = fmaf(wt[c], Wh[(size_t)c * kATT + a], acc);
        vpart[(size_t)cg * kATT + a] = acc;    // plain store, no atomics
        if (bid == 0 && threadIdx.x < 64) {
            float pb = 0.0f;
            #pragma unroll 4
            for (int c = threadIdx.x; c < kATT; c += 64)
                pb = fmaf(wt[c], bh[c], pb);
            #pragma unroll
            for (int off = 32; off > 0; off >>= 1)
                pb += __shfl_down(pb, off, 64);
            if (threadIdx.x == 0) beta[0] = pb + bt[0];
        }
        return;
    }
    int i = blockIdx.x * 256 + threadIdx.x;    // ---- cast part
    if (i < kN4a) {
        float4 f = ((const float4*)x1)[i];
        ushort4 o = { f2bf(f.x), f2bf(f.y), f2bf(f.z), f2bf(f.w) };
        ((ushort4*)x1b)[i] = o;
    } else if ((i -= kN4a) < kN4b) {
        float4 f = ((const float4*)W1)[i];
        ushort4 o = { f2bf(f.x), f2bf(f.y), f2bf(f.z), f2bf(f.w) };
        ((ushort4*)W1b)[i] = o;
    } else if ((i -= kN4b) < kN1) {
        int r = i / kD2p, c = i - r * kD2p;
        x2b[i] = (c < kD2) ? f2bf(x2[(size_t)r * kD2 + c]) : (unsigned short)0;
    } else if ((i -= kN1) < kN2) {
        int r = i / kD2p, c = i - r * kD2p;
        W2b[i] = (c < kD2) ? f2bf(W2[(size_t)r * kD2 + c]) : (unsigned short)0;
    }
}

// ---------------------------------------------------------------------------
// Fused GEMM dispatch (R7 mapping -- XCD chunking was null, R8):
//   [0, kP1Blocks): p1 128x128 dbuf, K-split 2 -> p1a/p1b
//   [+kP2Blocks):   p2 64x64
//   [+kInitBlocks): out[i] = beta
//   [+kVBlocks):    v[a] = sum_g vpart[g][a]
// ---------------------------------------------------------------------------
static constexpr int kP1Mt      = (kM + 127) / 128;              // 13
static constexpr int kP1Blocks  = kP1Mt * (kATT / 128) * 2;      // 208 (K-split 2)
static constexpr int kP2Blocks  = (kR2 / 64) * (kATT / 64);      // 160
static constexpr int kInitBlocks = (kOut + 255) / 256;           // 490
static constexpr int kVBlocks   = kATT / 256;                    // 4
static constexpr int kKHalf     = kD1 / 2;                       // 1024

__global__ __launch_bounds__(256) void gemm_all_kernel(
        const unsigned short* __restrict__ x2b, const unsigned short* __restrict__ W2b,
        float* __restrict__ p2w,
        const unsigned short* __restrict__ x1b, const unsigned short* __restrict__ W1b,
        float* __restrict__ p1a, float* __restrict__ p1b,
        const float* __restrict__ beta, float* __restrict__ outp,
        const float* __restrict__ vpart, float* __restrict__ v) {
    __shared__ unsigned short As2[2][128 * 64];   // 2 x 16 KB
    __shared__ unsigned short Bs2[2][128 * 64];   // 2 x 16 KB

    const int bid  = blockIdx.x;
    const int tid  = threadIdx.x;
    const int lane = tid & 63;
    const int wv   = tid >> 6;

    if (bid >= kP1Blocks + kP2Blocks) {
        int r = bid - kP1Blocks - kP2Blocks;
        if (r < kInitBlocks) {                 // ---- out = beta init
            int i = r * 256 + tid;
            if (i < kOut) outp[i] = beta[0];
        } else {                               // ---- v = sum of vpart slices
            int a = (r - kInitBlocks) * 256 + tid;
            float s = 0.0f;
            #pragma unroll
            for (int g = 0; g < kVPart; ++g)
                s += vpart[(size_t)g * kATT + a];
            v[a] = s;
        }
        return;
    }

    if (bid < kP1Blocks) {                     // ---- p1: 128x128 dbuf path
        const int l  = bid;
        const int ks = l & 1;                  // K-split half
        const int t  = l >> 1;                 // 0..103
        const int mx = t % kP1Mt, nx = t / kP1Mt;
        const int m0 = mx * 128, n0 = nx * 128;
        const int kBeg = ks * kKHalf;

        const int srow = tid >> 3;                         // 0..31
        const int kx   = ((tid & 7) ^ (srow & 7)) * 8;     // swizzled k-elems
        int ar[4], br[4];
        #pragma unroll
        for (int q = 0; q < 4; ++q) {
            ar[q] = min(m0 + srow + q * 32, kM - 1);
            br[q] = n0 + srow + q * 32;
        }
        const int wr = (wv >> 1) * 64;         // wave row offset in tile
        const int wc = (wv & 1) * 64;          // wave col offset in tile

        f32x4 acc[4][4] = {};

        // prologue: stage buf 0
        #pragma unroll
        for (int q = 0; q < 4; ++q) {
            load_lds16(x1b + (size_t)ar[q] * kD1 + kBeg + kx,
                       (char*)As2[0] + (tid + q * 256) * 16);
            load_lds16(W1b + (size_t)br[q] * kD1 + kBeg + kx,
                       (char*)Bs2[0] + (tid + q * 256) * 16);
        }
        __syncthreads();

        int buf = 0;
        for (int k0 = 0; k0 < kKHalf; k0 += 64) {
            if (k0 + 64 < kKHalf) {            // issue next-tile loads FIRST
                const int kp = kBeg + k0 + 64;
                #pragma unroll
                for (int q = 0; q < 4; ++q) {
                    load_lds16(x1b + (size_t)ar[q] * kD1 + kp + kx,
                               (char*)As2[buf ^ 1] + (tid + q * 256) * 16);
                    load_lds16(W1b + (size_t)br[q] * kD1 + kp + kx,
                               (char*)Bs2[buf ^ 1] + (tid + q * 256) * 16);
                }
            }
            const char* Ap = (const char*)As2[buf];
            const char* Bp = (const char*)Bs2[buf];
            #pragma unroll
            for (int kk = 0; kk < 2; ++kk) {
                bf16x8 af[4], bf[4];
                #pragma unroll
                for (int i = 0; i < 4; ++i) {
                    int r   = wr + i * 16 + (lane & 15);
                    int col = (kk * 64 + (lane >> 4) * 16) ^ ((r & 7) << 4);
                    af[i] = *(const bf16x8*)(Ap + r * 128 + col);
                }
                #pragma unroll
                for (int j = 0; j < 4; ++j) {
                    int r   = wc + j * 16 + (lane & 15);
                    int col = (kk * 64 + (lane >> 4) * 16) ^ ((r & 7) << 4);
                    bf[j] = *(const bf16x8*)(Bp + r * 128 + col);
                }
                #pragma unroll
                for (int i = 0; i < 4; ++i)
                    #pragma unroll
                    for (int j = 0; j < 4; ++j)
                        acc[i][j] = __builtin_amdgcn_mfma_f32_16x16x32_bf16(
                                        af[i], bf[j], acc[i][j], 0, 0, 0);
            }
            __syncthreads();                   // drains staged loads too
            buf ^= 1;
        }

        float* Co = ks ? p1b : p1a;
        #pragma unroll
        for (int i = 0; i < 4; ++i)
            #pragma unroll
            for (int j = 0; j < 4; ++j)
                #pragma unroll
                for (int r = 0; r < 4; ++r) {
                    int m = m0 + wr + i * 16 + (lane >> 4) * 4 + r;
                    int n = n0 + wc + j * 16 + (lane & 15);
                    if (m < kM) Co[(size_t)m * kATT + n] = kTanhScale * acc[i][j][r];
                }
        return;
    }

    // ---- p2: legacy 64x64 path (small: 0.42 GF)
    {
        const int l  = bid - kP1Blocks;
        const int mx = l % (kR2 / 64), nx = l / (kR2 / 64);
        const int m0 = mx * 64, n0 = nx * 64;
        unsigned short* As = As2[0];
        unsigned short* Bs = Bs2[0];

        const int mh = (wv >> 1) * 32;
        const int nh = (wv & 1) * 32;
        const int row0 = tid >> 3;
        const int kx   = ((tid & 7) ^ (row0 & 7)) * 8;
        const int ar0 = min(m0 + row0, kR2 - 1), ar1 = min(m0 + row0 + 32, kR2 - 1);
        const int br0 = n0 + row0,               br1 = n0 + row0 + 32;

        f32x4 acc[2][2] = {};
        for (int k0 = 0; k0 < kD2p; k0 += 64) {
            load_lds16(x2b + (size_t)ar0 * kD2p + k0 + kx, (char*)As + tid * 16);
            load_lds16(x2b + (size_t)ar1 * kD2p + k0 + kx, (char*)As + (tid + 256) * 16);
            load_lds16(W2b + (size_t)br0 * kD2p + k0 + kx, (char*)Bs + tid * 16);
            load_lds16(W2b + (size_t)br1 * kD2p + k0 + kx, (char*)Bs + (tid + 256) * 16);
            __syncthreads();

            #pragma unroll
            for (int kk = 0; kk < 2; ++kk) {
                bf16x8 af[2], bf[2];
                #pragma unroll
                for (int i = 0; i < 2; ++i) {
                    int r   = mh + i * 16 + (lane & 15);
                    int col = (kk * 64 + (lane >> 4) * 16) ^ ((r & 7) << 4);
                    af[i] = *(const bf16x8*)((const char*)As + r * 128 + col);
                }
                #pragma unroll
                for (int j = 0; j < 2; ++j) {
                    int r   = nh + j * 16 + (lane & 15);
                    int col = (kk * 64 + (lane >> 4) * 16) ^ ((r & 7) << 4);
                    bf[j] = *(const bf16x8*)((const char*)Bs + r * 128 + col);
                }
                #pragma unroll
                for (int i = 0; i < 2; ++i)
                    #pragma unroll
                    for (int j = 0; j < 2; ++j)
                        acc[i][j] = __builtin_amdgcn_mfma_f32_16x16x32_bf16(
                                        af[i], bf[j], acc[i][j], 0, 0, 0);
            }
            __syncthreads();
        }

        #pragma unroll
        for (int i = 0; i < 2; ++i)
            #pragma unroll
            for (int j = 0; j < 2; ++j)
                #pragma unroll
                for (int r = 0; r < 4; ++r) {
                    int m = m0 + mh + i * 16 + (lane >> 4) * 4 + r;
                    int n = n0 + nh + j * 16 + (lane & 15);
                    if (m < kR2) p2w[(size_t)m * kATT + n] = acc[i][j][r];
                }
    }
}

// ---------------------------------------------------------------------------
// alpha v7 = R10 alpha + packed-fp32 inner loop:
//   alpha is VALU-issue-bound (5 insts/elem x 128.5M elems = 32.7 us at
//   2-cyc issue == measured).  gfx950 VOP3P has v_pk_{mul,add,fma}_f32 --
//   express the non-trans ops as float2 ext-vector arithmetic so the
//   compiler can pack them: per 4 elems 20 -> 14 insts (2 pk_mul + 4 exp2
//   + 2 pk_add + 4 rcp + 2 pk_fma).  Accumulators are packed pairs summed
//   at the end (reduction-order delta ~1e-6, tol 2e-3).
//   Staging identical to R10: wsm [80][64] linear via global_load_lds
//   (reads are 16-lane broadcasts, conflict-free); us [16][68] padded,
//   manual (needs uA+uB add); v on the uniform path.
// grid (13, kB, 16); block 256 = 16 tp x 16 lg (5 l each).
// Each block atomicAdds into out (pre-set to beta by gemm dispatch).
// ---------------------------------------------------------------------------
__global__ __launch_bounds__(256) void alpha_kernel(
        const float* __restrict__ p1A, const float* __restrict__ p1B,
        const float* __restrict__ p2,
        const float* __restrict__ v, float* __restrict__ outp) {
    __shared__ float us[16][kPadA];          // 16 x 68 x 4 = 4.25 KB (padded)
    __shared__ float wsm[kL][kAChunk];       // 80 x 64 x 4 = 20 KB (linear)
    const int b     = blockIdx.y;
    const int as    = blockIdx.z;            // 0..15
    const int aBase = as * kAChunk;
    const int p0    = blockIdx.x * 16;
    const int tid   = threadIdx.x;
    const int tp    = tid & 15;              // p lane
    const int lg    = tid >> 4;              // l-group: l = lg*5 + j

    // ---- stage w via direct global->LDS DMA (5 chunks of 16 B per thread)
    #pragma unroll
    for (int q = 0; q < 5; ++q) {
        int idx = q * 256 + tid;             // 0..1279
        int row = idx >> 4, col = idx & 15;
        load_lds16(p2 + ((size_t)(b * kL + row)) * kATT + aBase + col * 4,
                   (char*)wsm + (size_t)idx * 16);
    }
    // ---- stage u (16 rows x 16 float4 cols, one per thread), summing halves
    {
        int row = tid >> 4, col = tid & 15;
        int gp  = min(p0 + row, kP - 1);
        size_t base = ((size_t)(b * kP + gp)) * kATT + aBase + col * 4;
        float4 ua = *(const float4*)(p1A + base);
        float4 ub = *(const float4*)(p1B + base);
        float4 s  = { ua.x + ub.x, ua.y + ub.y, ua.z + ub.z, ua.w + ub.w };
        *(float4*)&us[row][col * 4] = s;
    }
    __syncthreads();                         // drains DMA (vmcnt) + ds_write

    float sumV = 0.0f;
    f32x2 acc2[kLPer] = {};                  // packed partial sums
    #pragma unroll 4
    for (int a4 = 0; a4 < kAChunk / 4; ++a4) {
        const float4 vvs = *(const float4*)(v + aBase + a4 * 4);  // uniform
        sumV += vvs.x + vvs.y + vvs.z + vvs.w;
        const f32x2 vva = { vvs.x, vvs.y };
        const f32x2 vvb = { vvs.z, vvs.w };
        float4 uu = *(const float4*)&us[tp][a4 * 4];
        const f32x2 ua = { uu.x, uu.y };
        const f32x2 ub = { uu.z, uu.w };
        #pragma unroll
        for (int j = 0; j < kLPer; ++j) {
            const f32x2 wa = *(const f32x2*)&wsm[lg * kLPer + j][a4 * 4];
            const f32x2 wb = *(const f32x2*)&wsm[lg * kLPer + j][a4 * 4 + 2];
            f32x2 pa = ua * wa;                          // pk_mul
            f32x2 pb = ub * wb;
            f32x2 ea = { __builtin_amdgcn_exp2f(pa.x),   // scalar trans
                         __builtin_amdgcn_exp2f(pa.y) };
            f32x2 eb = { __builtin_amdgcn_exp2f(pb.x),
                         __builtin_amdgcn_exp2f(pb.y) };
            ea = ea + 1.0f;                              // pk_add
            eb = eb + 1.0f;
            f32x2 ra = { __builtin_amdgcn_rcpf(ea.x),    // scalar trans
                         __builtin_amdgcn_rcpf(ea.y) };
            f32x2 rb = { __builtin_amdgcn_rcpf(eb.x),
                         __builtin_amdgcn_rcpf(eb.y) };
            acc2[j] = acc2[j] + vva * ra;                // pk_fma
            acc2[j] = acc2[j] + vvb * rb;
        }
    }

    const int p = p0 + tp;
    if (p < kP) {
        float* po = outp + ((size_t)b * kL + lg * kLPer) * kP + p;
        #pragma unroll
        for (int j = 0; j < kLPer; ++j) {
            float a = acc2[j].x + acc2[j].y;
            atomicAdd(&po[(size_t)j * kP], sumV - 2.0f * a);
        }
    }
}

// ---------------------------------------------------------------------------
extern "C" void kernel_launch(void* const* d_in, const int* in_sizes, int n_in,
                              void* d_out, int out_size, void* d_ws, size_t ws_size,
                              hipStream_t stream) {
    const float* x1 = (const float*)d_in[0];
    const float* x2 = (const float*)d_in[1];
    const float* W1 = (const float*)d_in[2];
    const float* W2 = (const float*)d_in[3];
    const float* Wh = (const float*)d_in[4];
    const float* bh = (const float*)d_in[5];
    const float* wt = (const float*)d_in[6];
    const float* bt = (const float*)d_in[7];
    float* out = (float*)d_out;

    // workspace layout (floats first, then bf16):
    // v[1024] | vpart[16*1024] | beta pad->64 | p2w[640*1024]
    // | p1a[1568*1024] | p1b[1568*1024] | x1b | W1b | x2b | W2b   (~27 MB)
    float* ws    = (float*)d_ws;
    float* v     = ws;
    float* vpart = ws + 1024;
    float* beta  = vpart + (size_t)kVPart * kATT;
    float* p2w   = beta + 64;
    float* p1a   = p2w + (size_t)kR2 * kATT;
    float* p1b   = p1a + (size_t)kM * kATT;
    unsigned short* x1b = (unsigned short*)(p1b + (size_t)kM * kATT);
    unsigned short* W1b = x1b + (size_t)kM * kD1;
    unsigned short* x2b = W1b + (size_t)kATT * kD1;
    unsigned short* W2b = x2b + (size_t)kR2 * kD2p;

    prep_kernel<<<dim3(kCastBlocks + 64), 256, 0, stream>>>(
        x1, x1b, W1, W1b, x2, x2b, W2, W2b, Wh, wt, bh, bt, vpart, beta);
    gemm_all_kernel<<<dim3(kP1Blocks + kP2Blocks + kInitBlocks + kVBlocks),
                     256, 0, stream>>>(
        x2b, W2b, p2w, x1b, W1b, p1a, p1b, beta, out, vpart, v);
    alpha_kernel<<<dim3((kP + 15) / 16, kB, kASplit), 256, 0, stream>>>(
        p1a, p1b, p2w, v, out);
}